// Round 1
// baseline (1174.003 us; speedup 1.0000x reference)
//
#include <hip/hip_runtime.h>
#include <cstdint>
#include <cstddef>

// MLSMPO: multi-layer spaced-MPO network, MI355X implementation.
// Pipeline: embed1 -> scan(L1 left/right) -> epilogue1 -> embed2 ->
//           scan(L2) -> epilogue2(+cos/sin) -> final 80-step MPO chain.
// Mid-site weights: f16 (x256 scale, folded back via v/256) - they only feed
// the O(1e-3) correction term, so precision is safe. Output-site (Wsum) and
// all layer boundaries stay fp32.

typedef _Float16 h2_t __attribute__((ext_vector_type(2)));

__device__ __forceinline__ float fdot2f(uint32_t wa, uint32_t wb, float acc){
#if __has_builtin(__builtin_amdgcn_fdot2)
  union U { uint32_t u; h2_t h; };
  U a, b; a.u = wa; b.u = wb;
  return __builtin_amdgcn_fdot2(a.h, b.h, acc, false);
#else
  union U { uint32_t u; _Float16 h[2]; };
  U a, b; a.u = wa; b.u = wb;
  return acc + (float)a.h[0]*(float)b.h[0] + (float)a.h[1]*(float)b.h[1];
#endif
}

__device__ __forceinline__ uint32_t packh2(float a, float b){
  union { _Float16 h[2]; uint32_t u; } z;
  z.h[0] = (_Float16)a; z.h[1] = (_Float16)b; return z.u;
}

__device__ __forceinline__ unsigned short f16b(float x){
  union { _Float16 h; unsigned short u; } z;
  z.h = (_Float16)x; return z.u;
}

// ---------------- prep: Wmid (f32 [JT][64][64][2]) -> f16 planes x256 ----------------
// T layout: [jt][p][e][d]  (left scan / final: lane=e, contract d)
// N layout: [jt][p][d][e]  (right scan: lane=d, contract e)
__global__ void k_mid_planes(const float* __restrict__ W, unsigned short* __restrict__ T,
                             unsigned short* __restrict__ N, int JT){
  long tid = (long)blockIdx.x*256 + threadIdx.x;
  if (tid >= (long)JT*4096) return;
  int jt = (int)(tid >> 12), r = (int)(tid & 4095);
  int mode = blockIdx.z;
  if (mode == 0){
    int e = r >> 6, d = r & 63;
    float2 w = *(const float2*)(W + ((size_t)jt*4096 + (size_t)d*64 + e)*2);
    T[((size_t)jt*2+0)*4096 + (size_t)e*64 + d] = f16b(w.x*256.f);
    T[((size_t)jt*2+1)*4096 + (size_t)e*64 + d] = f16b(w.y*256.f);
  } else {
    int d = r >> 6, e = r & 63;
    float2 w = *(const float2*)(W + ((size_t)jt*4096 + (size_t)d*64 + e)*2);
    N[((size_t)jt*2+0)*4096 + (size_t)d*64 + e] = f16b(w.x*256.f);
    N[((size_t)jt*2+1)*4096 + (size_t)d*64 + e] = f16b(w.y*256.f);
  }
}

// ---------------- prep: Wout (f32 [J][64][64][2][9]) -> Wsum f32 (sum over f) ----------------
// T: [j][e][d] float2(p), N: [j][d][e] float2(p)
__global__ void k_wsum(const float* __restrict__ W, float2* __restrict__ T,
                       float2* __restrict__ N, int J){
  long tid = (long)blockIdx.x*256 + threadIdx.x;
  if (tid >= (long)J*4096) return;
  int j = (int)(tid >> 12), r = (int)(tid & 4095);
  int mode = blockIdx.z;
  int d, e;
  if (mode == 0){ e = r >> 6; d = r & 63; } else { d = r >> 6; e = r & 63; }
  const float* src = W + ((size_t)j*4096 + (size_t)d*64 + e)*18;
  float s0 = 0.f, s1 = 0.f;
  #pragma unroll
  for (int f = 0; f < 9; ++f){ s0 += src[f]; s1 += src[9+f]; }
  float2 v; v.x = s0; v.y = s1;
  (mode ? N : T)[(size_t)j*4096 + r] = v;
}

// ---------------- patch embed: image [B][Wd][Wd] -> unit vectors [B][PG*PG] ----------------
__global__ void k_embed(const float* __restrict__ img, int Wd, int PG,
                        float2* __restrict__ outv){
  int tid = blockIdx.x*256 + threadIdx.x;
  int NP = PG*PG;
  if (tid >= 128*NP) return;
  int b = tid / NP, s = tid - b*NP;
  int pi = s / PG, pj = s - pi*PG;
  const float* base = img + (size_t)b*Wd*Wd + (size_t)(3*pi)*Wd + 3*pj;
  float cs = 0.f, sn = 0.f;
  #pragma unroll
  for (int r = 0; r < 3; ++r){
    #pragma unroll
    for (int c = 0; c < 3; ++c){
      float x = base[r*Wd + c];
      float s_, c_; sincosf(1.5707963267948966f*x, &s_, &c_);
      cs += c_; sn += s_;
    }
  }
  cs *= (1.f/9.f); sn *= (1.f/9.f);
  float rn = rsqrtf(cs*cs + sn*sn);
  float2 v; v.x = cs*rn; v.y = sn*rn;
  outv[tid] = v;
}

// ---------------- scan inner ops ----------------
__device__ __forceinline__ float apply_mid(const unsigned short* Wrow, const uint32_t* lpkw,
                                           float lval, float vx, float vy){
  const uint4* r0 = (const uint4*)Wrow;            // p0 plane row (64 f16)
  const uint4* r1 = (const uint4*)(Wrow + 4096);   // p1 plane row
  const uint4* lp = (const uint4*)lpkw;
  float a0 = 0.f, a1 = 0.f;
  #pragma unroll
  for (int i = 0; i < 8; ++i){
    uint4 q  = lp[i];
    uint4 w0 = r0[i];
    uint4 w1 = r1[i];
    a0 = fdot2f(w0.x, q.x, a0); a0 = fdot2f(w0.y, q.y, a0);
    a0 = fdot2f(w0.z, q.z, a0); a0 = fdot2f(w0.w, q.w, a0);
    a1 = fdot2f(w1.x, q.x, a1); a1 = fdot2f(w1.y, q.y, a1);
    a1 = fdot2f(w1.z, q.z, a1); a1 = fdot2f(w1.w, q.w, a1);
  }
  return lval + vx*a0 + vy*a1;
}

__device__ __forceinline__ float apply_out(const float2* Wrow, const float* lsw,
                                           float vx, float vy){
  const float4* wr = (const float4*)Wrow;   // 64 float2 = 32 float4
  const float4* lf = (const float4*)lsw;
  float a0 = 0.f, a1 = 0.f;
  #pragma unroll
  for (int i = 0; i < 16; ++i){
    float4 l4 = lf[i];
    float4 wA = wr[2*i], wB = wr[2*i+1];
    a0 += l4.x*wA.x; a1 += l4.x*wA.y;
    a0 += l4.y*wA.z; a1 += l4.y*wA.w;
    a0 += l4.z*wB.x; a1 += l4.z*wB.y;
    a0 += l4.w*wB.z; a1 += l4.w*wB.w;
  }
  return vx*a0 + vy*a1;  // no identity term at output sites
}

#define STORE_STATE(val) do { \
    lsw[L] = (val); \
    float _o = __shfl_xor((val), 1); \
    lpw[L>>1] = packh2((L&1) ? _o : (val), (L&1) ? (val) : _o); \
  } while(0)

// One wave per (b, dir). dir=0: left env (saves L_j before output site),
// dir=1: right env (reversed groups, mids reversed, saves R_j before output-site apply).
__global__ __launch_bounds__(128) void k_scan(
    const float2* __restrict__ v,
    const unsigned short* __restrict__ WmT, const unsigned short* __restrict__ WmN,
    const float2* __restrict__ WsT, const float2* __restrict__ WsN,
    float* __restrict__ Lout, float* __restrict__ Rout, int J, int n){
  __shared__ __align__(16) float    lsh[2][64];
  __shared__ __align__(16) uint32_t lpk[2][32];
  const int w = threadIdx.x >> 6, L = threadIdx.x & 63;
  const int dir = blockIdx.y;
  const int b = blockIdx.x*2 + w;
  const unsigned short* Wm = dir ? WmN : WmT;
  const float2* Ws = dir ? WsN : WsT;
  float* Sout = dir ? Rout : Lout;
  const float2* vb = v + (size_t)b*n;
  float* lsw = lsh[w];
  uint32_t* lpw = lpk[w];
  const float INV = 1.f/256.f;
  float lval = (L == 0) ? 1.f : 0.f;
  STORE_STATE(lval);
  for (int g = 0; g < J; ++g){
    const int j = dir ? (J-1-g) : g;
    const unsigned short* Wj = Wm + (size_t)(j*8)*2*4096 + (size_t)L*64;
    const float2* Wsr = Ws + (size_t)j*4096 + (size_t)L*64;
    if (!dir){
      Sout[((size_t)j*128 + b)*64 + L] = lval;
      float2 vo = vb[j*9];
      lval = apply_out(Wsr, lsw, vo.x, vo.y);
      STORE_STATE(lval);
      for (int t = 1; t < 9; ++t){
        float2 vm = vb[j*9 + t];
        lval = apply_mid(Wj + (size_t)(t-1)*2*4096, lpw, lval, vm.x*INV, vm.y*INV);
        STORE_STATE(lval);
      }
    } else {
      for (int t = 8; t >= 1; --t){
        float2 vm = vb[j*9 + t];
        lval = apply_mid(Wj + (size_t)(t-1)*2*4096, lpw, lval, vm.x*INV, vm.y*INV);
        STORE_STATE(lval);
      }
      Sout[((size_t)j*128 + b)*64 + L] = lval;
      float2 vo = vb[j*9];
      lval = apply_out(Wsr, lsw, vo.x, vo.y);
      STORE_STATE(lval);
    }
  }
}

// ---------------- epilogue: out[b,j,f] = sum_{d,e,p} L[j,b,d] W[j,d,e,p,f] vo[b,p] R[j,b,e] ----
// block = (j, b-half of 64); 256 threads = 64 b x 4 e-quarters.
template<bool EMB>
__global__ __launch_bounds__(256) void k_out(
    const float* __restrict__ Wout, const float* __restrict__ Lbuf,
    const float* __restrict__ Rbuf, const float2* __restrict__ v, int n,
    float* __restrict__ hout, float2* __restrict__ vF){
  __shared__ float tile[8][64][20];   // 40 KB W chunk (d8, e, 18 pf) ; reused as reduction scratch
  __shared__ float Lsh[64][65];
  const int j = blockIdx.x, bh = blockIdx.y;
  const int q = threadIdx.x >> 6, bl = threadIdx.x & 63;
  const int b = bh*64 + bl;
  for (int idx = threadIdx.x; idx < 64*64; idx += 256){
    int r = idx >> 6, d = idx & 63;
    Lsh[r][d] = Lbuf[((size_t)j*128 + bh*64 + r)*64 + d];
  }
  float Rr[16];
  {
    const float4* Rp = (const float4*)(Rbuf + ((size_t)j*128 + b)*64 + q*16);
    #pragma unroll
    for (int i = 0; i < 4; ++i) ((float4*)Rr)[i] = Rp[i];
  }
  float acc[18];
  #pragma unroll
  for (int k = 0; k < 18; ++k) acc[k] = 0.f;
  __syncthreads();
  for (int c = 0; c < 8; ++c){
    #pragma unroll
    for (int k = 0; k < 2; ++k){
      int pi = threadIdx.x*2 + k;
      int d8 = pi >> 6, e = pi & 63;
      const float* src = Wout + ((size_t)(j*64 + c*8 + d8)*64 + e)*18;
      float* dst = &tile[d8][e][0];
      #pragma unroll
      for (int m = 0; m < 18; ++m) dst[m] = src[m];
    }
    __syncthreads();
    #pragma unroll 1
    for (int d8 = 0; d8 < 8; ++d8){
      float lw = Lsh[bl][c*8 + d8];
      #pragma unroll
      for (int i = 0; i < 16; ++i){
        int e = q*16 + i;
        float wbe = lw * Rr[i];
        const float* tp = &tile[d8][e][0];
        float4 t0 = *(const float4*)(tp);
        float4 t1 = *(const float4*)(tp+4);
        float4 t2 = *(const float4*)(tp+8);
        float4 t3 = *(const float4*)(tp+12);
        float2 t4 = *(const float2*)(tp+16);
        acc[0]  += wbe*t0.x; acc[1]  += wbe*t0.y; acc[2]  += wbe*t0.z; acc[3]  += wbe*t0.w;
        acc[4]  += wbe*t1.x; acc[5]  += wbe*t1.y; acc[6]  += wbe*t1.z; acc[7]  += wbe*t1.w;
        acc[8]  += wbe*t2.x; acc[9]  += wbe*t2.y; acc[10] += wbe*t2.z; acc[11] += wbe*t2.w;
        acc[12] += wbe*t3.x; acc[13] += wbe*t3.y; acc[14] += wbe*t3.z; acc[15] += wbe*t3.w;
        acc[16] += wbe*t4.x; acc[17] += wbe*t4.y;
      }
    }
    __syncthreads();
  }
  float* red = &tile[0][0][0];   // 4*64*20 floats = 20.5 KB, fits in tile
  #pragma unroll
  for (int k = 0; k < 18; ++k) red[((size_t)q*64 + bl)*20 + k] = acc[k];
  __syncthreads();
  if (q == 0){
    float s[18];
    #pragma unroll
    for (int k = 0; k < 18; ++k)
      s[k] = red[(size_t)bl*20+k] + red[(64+(size_t)bl)*20+k]
           + red[(128+(size_t)bl)*20+k] + red[(192+(size_t)bl)*20+k];
    float2 vo = v[(size_t)b*n + j*9];
    #pragma unroll
    for (int f = 0; f < 9; ++f){
      float val = vo.x*s[f] + vo.y*s[9+f];
      if (EMB){
        float s_, c_; sincosf(1.5707963267948966f*val, &s_, &c_);
        float2 e2; e2.x = c_; e2.y = s_;
        vF[(size_t)b*81 + j*9 + f] = e2;
      } else {
        hout[(size_t)b*729 + j*9 + f] = val;
      }
    }
  }
}

// ---------------- final layer: 80-step MPO chain on u[b,e,o] ----------------
// block per b; 4 waves split the 10 outputs {3,3,2,2} (+pad rows 10/11).
__global__ __launch_bounds__(256) void k_final(
    const float2* __restrict__ vF, const unsigned short* __restrict__ WTF,
    const float* __restrict__ A0f, float* __restrict__ outp){
  __shared__ __align__(16) uint32_t uh[12][32];
  const int w = threadIdx.x >> 6, L = threadIdx.x & 63;
  const int b = blockIdx.x;
  const int obase[4] = {0, 3, 6, 8};
  int o_[3];
  #pragma unroll
  for (int oi = 0; oi < 3; ++oi){
    int o = obase[w] + oi;
    if (w == 2 && oi == 2) o = 11;   // pad (wave3's oi=2 naturally lands on 10)
    o_[oi] = o;
  }
  float2 v0 = vF[(size_t)b*81];
  float u[3];
  #pragma unroll
  for (int oi = 0; oi < 3; ++oi){
    int oc = (o_[oi] < 10) ? o_[oi] : 0;
    u[oi] = v0.x*A0f[(L*2+0)*10 + oc] + v0.y*A0f[(L*2+1)*10 + oc];
  }
  #pragma unroll
  for (int oi = 0; oi < 3; ++oi){
    float ot = __shfl_xor(u[oi], 1);
    uh[o_[oi]][L>>1] = packh2((L&1) ? ot : u[oi], (L&1) ? u[oi] : ot);
  }
  __syncthreads();
  const float INV = 1.f/256.f;
  for (int t = 0; t < 80; ++t){
    float2 vv = vF[(size_t)b*81 + 1 + t];
    float vx = vv.x*INV, vy = vv.y*INV;
    const uint4* r0 = (const uint4*)(WTF + (size_t)(t*2+0)*4096 + (size_t)L*64);
    const uint4* r1 = (const uint4*)(WTF + (size_t)(t*2+1)*4096 + (size_t)L*64);
    uint4 a0[8], a1[8];
    #pragma unroll
    for (int i = 0; i < 8; ++i){ a0[i] = r0[i]; a1[i] = r1[i]; }
    float un[3];
    #pragma unroll
    for (int oi = 0; oi < 3; ++oi){
      const uint4* up = (const uint4*)uh[o_[oi]];
      float c0 = 0.f, c1 = 0.f;
      #pragma unroll
      for (int i = 0; i < 8; ++i){
        uint4 qq = up[i];
        c0 = fdot2f(a0[i].x, qq.x, c0); c0 = fdot2f(a0[i].y, qq.y, c0);
        c0 = fdot2f(a0[i].z, qq.z, c0); c0 = fdot2f(a0[i].w, qq.w, c0);
        c1 = fdot2f(a1[i].x, qq.x, c1); c1 = fdot2f(a1[i].y, qq.y, c1);
        c1 = fdot2f(a1[i].z, qq.z, c1); c1 = fdot2f(a1[i].w, qq.w, c1);
      }
      un[oi] = u[oi] + vx*c0 + vy*c1;
    }
    __syncthreads();
    #pragma unroll
    for (int oi = 0; oi < 3; ++oi){
      u[oi] = un[oi];
      float ot = __shfl_xor(u[oi], 1);
      uh[o_[oi]][L>>1] = packh2((L&1) ? ot : u[oi], (L&1) ? u[oi] : ot);
    }
    __syncthreads();
  }
  if (L == 0){
    #pragma unroll
    for (int oi = 0; oi < 3; ++oi)
      if (o_[oi] < 10) outp[(size_t)b*10 + o_[oi]] = u[oi];
  }
}

// ---------------- host ----------------
extern "C" void kernel_launch(void* const* d_in, const int* in_sizes, int n_in,
                              void* d_out, int out_size, void* d_ws, size_t ws_size,
                              hipStream_t stream){
  const float* x     = (const float*)d_in[0];
  const float* Wout0 = (const float*)d_in[1];
  const float* Wmid0 = (const float*)d_in[2];
  const float* Wout1 = (const float*)d_in[3];
  const float* Wmid1 = (const float*)d_in[4];
  const float* A0f   = (const float*)d_in[5];
  const float* WmidF = (const float*)d_in[6];
  float* outp = (float*)d_out;

  char* ws = (char*)d_ws;
  size_t off = 0;
  auto alloc = [&](size_t bytes) -> char* {
    char* p = ws + off;
    off = (off + bytes + 255) & ~(size_t)255;
    return p;
  };
  unsigned short* WmT0 = (unsigned short*)alloc((size_t)648*2*4096*2);
  unsigned short* WmN0 = (unsigned short*)alloc((size_t)648*2*4096*2);
  unsigned short* WmT1 = (unsigned short*)alloc((size_t)72*2*4096*2);
  unsigned short* WmN1 = (unsigned short*)alloc((size_t)72*2*4096*2);
  unsigned short* WTF  = (unsigned short*)alloc((size_t)80*2*4096*2);
  float2* WsT0 = (float2*)alloc((size_t)81*4096*8);
  float2* WsN0 = (float2*)alloc((size_t)81*4096*8);
  float2* WsT1 = (float2*)alloc((size_t)9*4096*8);
  float2* WsN1 = (float2*)alloc((size_t)9*4096*8);
  float2* v0 = (float2*)alloc((size_t)128*729*8);
  float2* v1 = (float2*)alloc((size_t)128*81*8);
  float2* vF = (float2*)alloc((size_t)128*81*8);
  float* L0 = (float*)alloc((size_t)81*128*64*4);
  float* R0 = (float*)alloc((size_t)81*128*64*4);
  float* L1 = (float*)alloc((size_t)9*128*64*4);
  float* R1 = (float*)alloc((size_t)9*128*64*4);
  float* h1 = (float*)alloc((size_t)128*729*4);
  (void)ws_size; (void)in_sizes; (void)n_in; (void)out_size;

  // prep
  k_mid_planes<<<dim3(10368,1,2), 256, 0, stream>>>(Wmid0, WmT0, WmN0, 648);
  k_mid_planes<<<dim3(1152,1,2),  256, 0, stream>>>(Wmid1, WmT1, WmN1, 72);
  k_mid_planes<<<dim3(1280,1,1),  256, 0, stream>>>(WmidF, WTF, (unsigned short*)nullptr, 80);
  k_wsum<<<dim3(1296,1,2), 256, 0, stream>>>(Wout0, WsT0, WsN0, 81);
  k_wsum<<<dim3(144,1,2),  256, 0, stream>>>(Wout1, WsT1, WsN1, 9);

  // layer 1
  k_embed<<<dim3(365), 256, 0, stream>>>(x, 81, 27, v0);
  k_scan<<<dim3(64,2), 128, 0, stream>>>(v0, WmT0, WmN0, WsT0, WsN0, L0, R0, 81, 729);
  k_out<false><<<dim3(81,2), 256, 0, stream>>>(Wout0, L0, R0, v0, 729, h1, (float2*)nullptr);

  // layer 2
  k_embed<<<dim3(41), 256, 0, stream>>>(h1, 27, 9, v1);
  k_scan<<<dim3(64,2), 128, 0, stream>>>(v1, WmT1, WmN1, WsT1, WsN1, L1, R1, 9, 81);
  k_out<true><<<dim3(9,2), 256, 0, stream>>>(Wout1, L1, R1, v1, 81, (float*)nullptr, vF);

  // final layer
  k_final<<<dim3(128), 256, 0, stream>>>(vF, WTF, A0f, outp);
}